// Round 9
// baseline (611.708 us; speedup 1.0000x reference)
//
#include <hip/hip_runtime.h>

// Problem constants
#define H_    128
#define W_    128
#define C_    3
#define PAD_  10
#define LWID  117          // LW = LH = 117
#define L_    13689        // LH*LW
#define LPAD  13696        // 107 * 128
#define D_    3072         // C*KH*KW
#define NMEM_ 4096

#define T_MARGIN 3.0f      // candidate margin; i8-quant score err sigma ~0.32 (9 sigma)
#define CAP_     256       // per-row candidate list capacity
#define SCAP_    64        // rescue shortlist capacity (expected ~1.4)

#define PSCALE 127.0f      // patch quant scale (p in [0,1))
#define MSCALE 32.0f       // mem quant scale (clip +-3.97)
#define INVS   (1.0f / (PSCALE * MSCALE))

typedef int   intx4  __attribute__((ext_vector_type(4)));

// Static device-side scratch (bss) — no d_ws dependency
__device__ int                g_best[L_];
__device__ int                g_pat[L_];     // mapping[g_best[l]] resolved in rescue
__device__ float              g_bias[NMEM_];
__device__ unsigned           g_max;
__device__ int                g_cnt[LPAD];
__device__ unsigned long long g_list[(size_t)LPAD * CAP_];   // 28 MB
__device__ char               g_A[(size_t)LPAD * D_];        // 42 MB i8 patches
__device__ char               g_B[(size_t)NMEM_ * D_];       // 12.6 MB i8 mem
__device__ float              g_part[4][H_ * W_ * C_];       // fold partials, 786 KB

__device__ __forceinline__ unsigned sortable(float f) {
    unsigned b = __float_as_uint(f);
    return (b & 0x80000000u) ? ~b : (b | 0x80000000u);
}
__device__ __forceinline__ float unsortable(unsigned u) {
    unsigned b = (u & 0x80000000u) ? (u & 0x7FFFFFFFu) : ~u;
    return __uint_as_float(b);
}
__device__ __forceinline__ unsigned long long packkey(float s, int n) {
    // max-key == max score; ties -> smaller n (jnp.argmax first-index)
    return ((unsigned long long)sortable(s) << 32) | (unsigned)(~n);
}

// async global->LDS, 16 bytes per lane (global_load_lds_dwordx4)
__device__ __forceinline__ void gl_lds16(const char* g, char* l) {
    __builtin_amdgcn_global_load_lds(
        (const __attribute__((address_space(1))) unsigned int*)(g),
        (__attribute__((address_space(3))) unsigned int*)(l), 16, 0, 0);
}

__device__ __forceinline__ int pack4(int a, int b, int c, int d) {
    return (a & 255) | ((b & 255) << 8) | ((c & 255) << 16) | ((d & 255) << 24);
}

// ---- fused prep: quantize mem + bias | build+quantize patches | zero cnts ---
__global__ __launch_bounds__(256)
void prep(const float* __restrict__ img, const float* __restrict__ mem)
{
    const int b = blockIdx.x;
    if (b < NMEM_) {
        const int n = b;
        const float4* row = (const float4*)(mem + (size_t)n * D_);
        int* q8 = (int*)(g_B + (size_t)n * D_);
        float s = 0.f;
        for (int q = threadIdx.x; q < D_ / 4; q += 256) {
            float4 v = row[q];
            int q0 = __float2int_rn(fminf(fmaxf(v.x * MSCALE, -127.f), 127.f));
            int q1 = __float2int_rn(fminf(fmaxf(v.y * MSCALE, -127.f), 127.f));
            int q2 = __float2int_rn(fminf(fmaxf(v.z * MSCALE, -127.f), 127.f));
            int q3 = __float2int_rn(fminf(fmaxf(v.w * MSCALE, -127.f), 127.f));
            q8[q] = pack4(q0, q1, q2, q3);
            s = fmaf(v.x, v.x, s); s = fmaf(v.y, v.y, s);
            s = fmaf(v.z, v.z, s); s = fmaf(v.w, v.w, s);
        }
        #pragma unroll
        for (int m = 32; m >= 1; m >>= 1) s += __shfl_down(s, m, 64);
        __shared__ float red[4];
        int lane = threadIdx.x & 63, w = threadIdx.x >> 6;
        if (lane == 0) red[w] = s;
        __syncthreads();
        if (threadIdx.x == 0) g_bias[n] = -0.5f * (red[0] + red[1] + red[2] + red[3]);
    } else {
        const int l = b - NMEM_;            // 0..LPAD-1 (pad rows -> zeros)
        if (threadIdx.x == 0) { g_cnt[l] = 0; if (l == 0) g_max = 0u; }
        const int py = l / LWID, px = l - (l / LWID) * LWID;
        const bool vl = l < L_;
        int* q8 = (int*)(g_A + (size_t)l * D_);
        for (int q = threadIdx.x; q < D_ / 4; q += 256) {
            int d = q * 4;
            int c = d >> 10, rem = d & 1023, kh = rem >> 5, kw0 = rem & 31;
            int qv[4] = {0, 0, 0, 0};
            if (vl) {
                int y = py + kh - PAD_;
                if ((unsigned)y < (unsigned)H_) {
                    int xb = px + kw0 - PAD_;
                    const float* ip = img + (size_t)y * (W_ * C_) + c;
                    #pragma unroll
                    for (int t = 0; t < 4; t++) {
                        int x = xb + t;
                        if ((unsigned)x < (unsigned)W_)
                            qv[t] = __float2int_rn(ip[x * C_] * PSCALE);
                    }
                }
            }
            q8[q] = pack4(qv[0], qv[1], qv[2], qv[3]);
        }
    }
}

// ---- i8 MFMA GEMM, 128l x 128n tile, BK=64 double-buffered, 4 blocks/CU -----
// Round-9: the untested quadrant — pipelining AT high occupancy. r1-r3 dbuf
// variants ran 1 blk/CU (128KB LDS) and lost the cross-block overlap; r6's
// 4-blk/CU structure still drains vmcnt(0) at every __syncthreads (loads
// issued ~0 cyc before the wait). BK=64 ping-pong fits the SAME 33KB budget:
// 2x(sA 8K + sB 8K) = 32KB -> 4 blk/CU kept, and the wait becomes
// s_waitcnt vmcnt(4) on loads issued one full iteration (~2000 cyc) earlier.
// Raw s_barrier (never __syncthreads: compiler re-inserts vmcnt(0));
// sched_barrier(0) after every waitcnt (rule 18: MFMA hoists past inline-asm
// lgkmcnt despite "memory" clobber -> stale LDS).
// BK=64 swizzle (4 slots/row): jj = kg ^ (r&3) ^ ((r>>2)&3). 16-lane phase
// (same kgrp, rows r..r+15) hits slot (4*(r&1) + jj) mod 8 -> all 8 slots,
// 2 lanes each = 2-way = free (m136). Involution verified both sides.
__global__ __launch_bounds__(256, 4)
void gemm_scores()
{
    __shared__ char sA[2][128 * 64];   // 2 x 8 KB
    __shared__ char sB[2][128 * 64];   // 2 x 8 KB
    __shared__ float biasS[128];

    const int tid = threadIdx.x;
    const int b = blockIdx.x;
    const int nt = (b & 7) * 4 + ((b >> 3) & 3);   // 0..31
    const int lt = b >> 5;                          // 0..106
    const int l0 = lt * 128;
    const int n0 = nt * 128;

    if (tid < 128) biasS[tid] = g_bias[n0 + tid];

    const int wave = tid >> 6, lane = tid & 63;
    const int wy = wave >> 1, wx = wave & 1;      // wave tile: 64l x 64n
    const int mrow = lane & 15, kgrp = lane >> 4;

    intx4 acc[4][4];
    #pragma unroll
    for (int i = 0; i < 4; i++)
        #pragma unroll
        for (int j = 0; j < 4; j++) acc[i][j] = (intx4){0, 0, 0, 0};

    const char* Ab = g_A + (size_t)l0 * D_;
    const char* Bb = g_B + (size_t)n0 * D_;

    // stage one K=64 slice (A 512 + B 512 chunks; 2+2 gl_lds per thread).
    // chunk c: row=c>>2, slot s=c&3; content k-offset jj = s^(r&3)^((r>>2)&3).
    auto stage = [&](int buf, int dd) {
        #pragma unroll
        for (int t = 0; t < 2; t++) {
            int c = tid + 256 * t;
            int row = c >> 2;
            int jj = (c & 3) ^ (row & 3) ^ ((row >> 2) & 3);
            gl_lds16(Ab + (size_t)row * D_ + dd + jj * 16, &sA[buf][c * 16]);
        }
        #pragma unroll
        for (int t = 0; t < 2; t++) {
            int c = tid + 256 * t;
            int row = c >> 2;
            int jj = (c & 3) ^ (row & 3) ^ ((row >> 2) & 3);
            gl_lds16(Bb + (size_t)row * D_ + dd + jj * 16, &sB[buf][c * 16]);
        }
    };

    // read addr for row r, k-group kg (16B): slot = kg ^ (r&3) ^ ((r>>2)&3)
    auto lds_off = [&](int r, int kg) {
        return (r * 4 + (kg ^ (r & 3) ^ ((r >> 2) & 3))) * 16;
    };

    auto compute = [&](int buf) {
        intx4 a[4], bf[4];
        #pragma unroll
        for (int i = 0; i < 4; i++)
            a[i] = *(const intx4*)&sA[buf][lds_off(wy * 64 + i * 16 + mrow, kgrp)];
        #pragma unroll
        for (int j = 0; j < 4; j++)
            bf[j] = *(const intx4*)&sB[buf][lds_off(wx * 64 + j * 16 + mrow, kgrp)];
        asm volatile("s_waitcnt lgkmcnt(0)" ::: "memory");
        __builtin_amdgcn_sched_barrier(0);
        #pragma unroll
        for (int i = 0; i < 4; i++)
            #pragma unroll
            for (int j = 0; j < 4; j++)
                acc[i][j] = __builtin_amdgcn_mfma_i32_16x16x64_i8(a[i], bf[j], acc[i][j], 0, 0, 0);
    };

    // prologue: stage K-step 0 into buf 0
    stage(0, 0);

    // main loop: 47 pipelined steps. stage(next) first; vmcnt(4) waits only
    // for cur's 4 loads (issued last iteration), the 4 just-issued stay in
    // flight across the barrier. Bottom barrier: all waves' ds_reads of cur
    // done (lgkmcnt(0) before MFMA) before next iter's stage overwrites it.
    #pragma unroll 1
    for (int it = 0; it < 47; ++it) {
        const int cur = it & 1;
        stage(cur ^ 1, (it + 1) << 6);
        asm volatile("s_waitcnt vmcnt(4)" ::: "memory");
        __builtin_amdgcn_sched_barrier(0);
        __builtin_amdgcn_s_barrier();
        compute(cur);
        __builtin_amdgcn_s_barrier();
    }
    // final step: drain all, compute buf 1
    asm volatile("s_waitcnt vmcnt(0)" ::: "memory");
    __builtin_amdgcn_sched_barrier(0);
    __builtin_amdgcn_s_barrier();
    compute(1);

    // epilogue. C/D layout: col = lane&15 (mrow), row = kgrp*4 + reg.
    // 16-lane group max covers this wave's full 64-col n-slice; threshold is
    // a per-slice lower bound of the row max (extra candidates are pruned in
    // reduce_rescue against the global row max — semantics unchanged).
    #pragma unroll
    for (int i = 0; i < 4; i++) {
        #pragma unroll
        for (int r = 0; r < 4; r++) {
            const int lrow = l0 + wy * 64 + i * 16 + kgrp * 4 + r;
            float sc[4];
            #pragma unroll
            for (int j = 0; j < 4; j++)
                sc[j] = (float)acc[i][j][r] * INVS + biasS[wx * 64 + j * 16 + mrow];
            float bestv = sc[0]; int bestj = 0;
            #pragma unroll
            for (int j = 1; j < 4; j++)
                if (sc[j] > bestv) { bestv = sc[j]; bestj = j; }
            unsigned long long key = packkey(bestv, n0 + wx * 64 + bestj * 16 + mrow);
            #pragma unroll
            for (int m = 1; m < 16; m <<= 1) {
                unsigned long long o = __shfl_xor(key, m, 64);
                if (o > key) key = o;
            }
            float thr = unsortable((unsigned)(key >> 32)) - T_MARGIN;
            #pragma unroll
            for (int j = 0; j < 4; j++) {
                if (sc[j] >= thr) {
                    int pos = atomicAdd(&g_cnt[lrow], 1);
                    if (pos < CAP_)
                        g_list[(size_t)lrow * CAP_ + pos] =
                            packkey(sc[j], n0 + wx * 64 + j * 16 + mrow);
                }
            }
        }
    }
}

// ---- per-row shortlist + exact fp32 rescore + pattern resolve ---------------
// kk==1 early exit (r4, bit-identical); patch staged to LDS once; one wave
// per candidate, coalesced float4 dot, barrier-free loop (r8, neutral-kept).
__global__ __launch_bounds__(256)
void reduce_rescue(const float* __restrict__ img, const float* __restrict__ mem,
                   const int* __restrict__ mapping)
{
    const int l = blockIdx.x;
    const int tid = threadIdx.x;
    const int lane = tid & 63, wave = tid >> 6;

    __shared__ unsigned long long redk[4];
    __shared__ int   scand[SCAP_];
    __shared__ int   scnt;
    __shared__ float patch[D_];            // 12 KB staged fp32 patch

    if (tid == 0) scnt = 0;
    int cnt = g_cnt[l];
    bool full = cnt > CAP_;
    __syncthreads();

    if (!full) {
        int k = cnt;
        const unsigned long long* lst = g_list + (size_t)l * CAP_;
        unsigned long long mk = 0ull;
        for (int q = tid; q < k; q += 256) {
            unsigned long long e = lst[q];
            if (e > mk) mk = e;
        }
        #pragma unroll
        for (int m = 32; m >= 1; m >>= 1) {
            unsigned long long o = __shfl_xor(mk, m, 64);
            if (o > mk) mk = o;
        }
        if (lane == 0) redk[wave] = mk;
        __syncthreads();
        unsigned long long rowk = redk[0];
        #pragma unroll
        for (int w = 1; w < 4; w++) if (redk[w] > rowk) rowk = redk[w];
        float thr = unsortable((unsigned)(rowk >> 32)) - T_MARGIN;
        for (int q = tid; q < k; q += 256) {
            unsigned long long e = lst[q];
            if (unsortable((unsigned)(e >> 32)) >= thr) {
                int p = atomicAdd(&scnt, 1);
                if (p < SCAP_) scand[p] = (int)(~(unsigned)(e & 0xFFFFFFFFull));
            }
        }
    }
    __syncthreads();
    bool scanall = full || (scnt > SCAP_);
    int kk = scanall ? NMEM_ : scnt;

    // early exit: a single shortlist candidate IS the argmax (exact semantics)
    if (!scanall && kk == 1) {
        if (tid == 0) { int n = scand[0]; g_best[l] = n; g_pat[l] = mapping[n]; }
        return;
    }

    // stage fp32 patch once (torch-unfold order: d = c*1024 + kh*32 + kw)
    const int py = l / LWID, px = l - (l / LWID) * LWID;
    for (int d = tid; d < D_; d += 256) {
        int c = d >> 10, rem = d & 1023, kh = rem >> 5, kw = rem & 31;
        int y = py + kh - PAD_, x = px + kw - PAD_;
        patch[d] = ((unsigned)y < (unsigned)H_ && (unsigned)x < (unsigned)W_)
                   ? img[((size_t)y * W_ + x) * C_ + c] : 0.f;
    }
    __syncthreads();

    // wave-per-candidate exact fp32 rescore, barrier-free loop
    const float4* pp = (const float4*)patch;
    unsigned long long bk = 0ull;
    for (int q = wave; q < kk; q += 4) {
        int n = scanall ? q : scand[q];
        const float4* mr = (const float4*)(mem + (size_t)n * D_);
        float s = 0.f;
        #pragma unroll
        for (int i = 0; i < 12; i++) {
            float4 m4 = mr[i * 64 + lane];
            float4 p4 = pp[i * 64 + lane];
            s = fmaf(m4.x, p4.x, s); s = fmaf(m4.y, p4.y, s);
            s = fmaf(m4.z, p4.z, s); s = fmaf(m4.w, p4.w, s);
        }
        #pragma unroll
        for (int sh = 32; sh >= 1; sh >>= 1) s += __shfl_xor(s, sh, 64);
        unsigned long long key = packkey(s + g_bias[n], n);
        if (key > bk) bk = key;
    }
    if (lane == 0) redk[wave] = bk;
    __syncthreads();
    if (tid == 0) {
        unsigned long long best = redk[0];
        #pragma unroll
        for (int w = 1; w < 4; w++) if (redk[w] > best) best = redk[w];
        int n = (int)(~(unsigned)(best & 0xFFFFFFFFull));
        g_best[l] = n; g_pat[l] = mapping[n];
    }
}

// ---- gather-fold: coalesced, py-quartered for parallelism -------------------
__global__ __launch_bounds__(128)
void gather_fold(const float* __restrict__ mem2)
{
    const int y = blockIdx.x;
    const int c = blockIdx.y;
    const int q = blockIdx.z;
    const int x = threadIdx.x;            // 0..127
    const int wv = x >> 6;

    const int py_lo = max(0, y - 21);
    const int py_hi = min(LWID - 1, y + PAD_);
    const int p0 = py_lo + q * 8;
    const int p1 = min(p0 + 8, py_hi + 1);
    const int nrows = (p1 > p0) ? (p1 - p0) : 0;

    __shared__ int patS[8 * LWID];
    for (int i = x; i < nrows * LWID; i += 128) {
        int rr = i / LWID, cc = i - rr * LWID;
        patS[i] = g_pat[(p0 + rr) * LWID + cc];
    }
    __syncthreads();

    const int slo = wv ? 43 : 0;
    const int shi = wv ? 116 : 73;

    float acc = 0.f;
    for (int py = p0; py < p1; ++py) {
        const int kh = y + PAD_ - py;                 // 0..31
        const int dbase = c * 1024 + kh * 32;
        const int* prow = &patS[(py - p0) * LWID];
        for (int s = slo; s <= shi; ++s) {
            int d = x + PAD_ - s;                     // lane-linear
            if ((unsigned)d < 32u)
                acc += mem2[(size_t)prow[s] * D_ + dbase + d];
        }
    }
    g_part[q][((size_t)y * W_ + x) * C_ + c] = acc;
}

// ---- sum partials + global max ----------------------------------------------
__global__ __launch_bounds__(256)
void maxfind(float* __restrict__ out)
{
    int i = blockIdx.x * 256 + threadIdx.x;           // 192*256 == 49152 exact
    float v = g_part[0][i] + g_part[1][i] + g_part[2][i] + g_part[3][i];
    out[i] = v;
    float m = v;
    #pragma unroll
    for (int s = 32; s >= 1; s >>= 1) m = fmaxf(m, __shfl_xor(m, s, 64));
    if ((threadIdx.x & 63) == 0) atomicMax(&g_max, sortable(m));
}

__global__ __launch_bounds__(256)
void normalize_k(float* __restrict__ out)
{
    int i = blockIdx.x * 256 + threadIdx.x;
    float mx = unsortable(g_max);
    out[i] = out[i] / mx;
}

extern "C" void kernel_launch(void* const* d_in, const int* in_sizes, int n_in,
                              void* d_out, int out_size, void* d_ws, size_t ws_size,
                              hipStream_t stream)
{
    const float* img     = (const float*)d_in[0];   // (128,128,3)
    const float* mem     = (const float*)d_in[1];   // (4096,3072)
    const float* mem2    = (const float*)d_in[2];   // (4096,3072)
    const int*   mapping = (const int*)d_in[3];     // (4096,)
    float* out = (float*)d_out;                     // (128,128,3)

    prep<<<NMEM_ + LPAD, 256, 0, stream>>>(img, mem);
    gemm_scores<<<(NMEM_ / 128) * (LPAD / 128), 256, 0, stream>>>();
    reduce_rescue<<<L_, 256, 0, stream>>>(img, mem, mapping);
    gather_fold<<<dim3(H_, C_, 4), 128, 0, stream>>>(mem2);
    maxfind<<<192, 256, 0, stream>>>(out);
    normalize_k<<<192, 256, 0, stream>>>(out);
}

// Round 10
// 475.459 us; speedup vs baseline: 1.2866x; 1.2866x over previous
//
#include <hip/hip_runtime.h>

// Problem constants
#define H_    128
#define W_    128
#define C_    3
#define PAD_  10
#define LWID  117          // LW = LH = 117
#define L_    13689        // LH*LW
#define LPAD  13696        // 107 * 128
#define D_    3072         // C*KH*KW
#define NMEM_ 4096

#define T_MARGIN 3.0f      // candidate margin; i8-quant score err sigma ~0.32 (9 sigma)
#define CAP_     256       // per-row candidate list capacity
#define SCAP_    64        // rescue shortlist capacity (expected ~1.4)

#define PSCALE 127.0f      // patch quant scale (p in [0,1))
#define MSCALE 32.0f       // mem quant scale (clip +-3.97)
#define INVS   (1.0f / (PSCALE * MSCALE))

// shifted quantized-image table: g_Q[s][c][y][j] = qimg[c][y][j+s]
// (y,j in padded coords, row stride 160, 160 rows; 16 shift copies so any
// 16B window (px+kw0) is a 16-aligned load from copy s=(px+kw0)&15)
#define QROWS 160
#define QSTR  160
#define QPLANE (QROWS * QSTR)          // 25600 per (s,c)

typedef int   intx4  __attribute__((ext_vector_type(4)));

// Static device-side scratch (bss) — no d_ws dependency
__device__ int                g_best[L_];
__device__ int                g_pat[L_];     // mapping[g_best[l]] resolved in rescue
__device__ float              g_bias[NMEM_];
__device__ unsigned           g_max;
__device__ int                g_cnt[LPAD];
__device__ unsigned long long g_list[(size_t)LPAD * CAP_];   // 28 MB
__device__ __align__(16) char g_Q[16 * 3 * QPLANE];          // 1.23 MB
__device__ char               g_B[(size_t)NMEM_ * D_];       // 12.6 MB i8 mem
__device__ float              g_part[4][H_ * W_ * C_];       // fold partials, 786 KB

__device__ __forceinline__ unsigned sortable(float f) {
    unsigned b = __float_as_uint(f);
    return (b & 0x80000000u) ? ~b : (b | 0x80000000u);
}
__device__ __forceinline__ float unsortable(unsigned u) {
    unsigned b = (u & 0x80000000u) ? (u & 0x7FFFFFFFu) : ~u;
    return __uint_as_float(b);
}
__device__ __forceinline__ unsigned long long packkey(float s, int n) {
    // max-key == max score; ties -> smaller n (jnp.argmax first-index)
    return ((unsigned long long)sortable(s) << 32) | (unsigned)(~n);
}

// async global->LDS, 16 bytes per lane (global_load_lds_dwordx4)
__device__ __forceinline__ void gl_lds16(const char* g, char* l) {
    __builtin_amdgcn_global_load_lds(
        (const __attribute__((address_space(1))) unsigned int*)(g),
        (__attribute__((address_space(3))) unsigned int*)(l), 16, 0, 0);
}

__device__ __forceinline__ int pack4(int a, int b, int c, int d) {
    return (a & 255) | ((b & 255) << 8) | ((c & 255) << 16) | ((d & 255) << 24);
}

// ---- fused prep: quantize mem + bias | build g_Q shift table | zero cnts ----
// Round-10: the 42 MB g_A materialization is gone. A[l][d] is just
// qimg[c][py+kh][px+kw]; the GEMM now stages A straight from g_Q (1.2 MB,
// L2-hot). prep's patch branch becomes a tiny shift-table build: block
// bb=b-NMEM_ (0..7679) decodes (s,c,y); thread j<160 writes one byte
// g_Q[s][c][y][j] = quant(img[y-PAD][j+s-PAD][c]) (0 outside). Bit-identical
// to the old g_A content. cnt zeroing folded in via bb*256+tid.
__global__ __launch_bounds__(256)
void prep(const float* __restrict__ img, const float* __restrict__ mem)
{
    const int b = blockIdx.x;
    if (b < NMEM_) {
        const int n = b;
        const float4* row = (const float4*)(mem + (size_t)n * D_);
        int* q8 = (int*)(g_B + (size_t)n * D_);
        float s = 0.f;
        for (int q = threadIdx.x; q < D_ / 4; q += 256) {
            float4 v = row[q];
            int q0 = __float2int_rn(fminf(fmaxf(v.x * MSCALE, -127.f), 127.f));
            int q1 = __float2int_rn(fminf(fmaxf(v.y * MSCALE, -127.f), 127.f));
            int q2 = __float2int_rn(fminf(fmaxf(v.z * MSCALE, -127.f), 127.f));
            int q3 = __float2int_rn(fminf(fmaxf(v.w * MSCALE, -127.f), 127.f));
            q8[q] = pack4(q0, q1, q2, q3);
            s = fmaf(v.x, v.x, s); s = fmaf(v.y, v.y, s);
            s = fmaf(v.z, v.z, s); s = fmaf(v.w, v.w, s);
        }
        #pragma unroll
        for (int m = 32; m >= 1; m >>= 1) s += __shfl_down(s, m, 64);
        __shared__ float red[4];
        int lane = threadIdx.x & 63, w = threadIdx.x >> 6;
        if (lane == 0) red[w] = s;
        __syncthreads();
        if (threadIdx.x == 0) g_bias[n] = -0.5f * (red[0] + red[1] + red[2] + red[3]);
    } else {
        const int bb = b - NMEM_;              // 0..7679 = (s,c,y)
        const int tid = threadIdx.x;
        // zero candidate counters (7680*256 covers LPAD)
        int g = bb * 256 + tid;
        if (g < LPAD) g_cnt[g] = 0;
        if (g == 0) g_max = 0u;
        // build one shift-table row
        const int sft = bb / (3 * QROWS);
        const int rem = bb - sft * (3 * QROWS);
        const int c = rem / QROWS;
        const int y = rem - c * QROWS;
        if (tid < QSTR) {
            const int yy = y - PAD_;
            const int x = tid + sft - PAD_;
            char v = 0;
            if ((unsigned)yy < (unsigned)H_ && (unsigned)x < (unsigned)W_)
                v = (char)__float2int_rn(img[((size_t)yy * W_ + x) * C_ + c] * PSCALE);
            g_Q[(size_t)((sft * 3 + c) * QROWS + y) * QSTR + tid] = v;
        }
    }
}

// ---- i8 MFMA GEMM, 128l x 128n tile, BK=128, 4 blocks/CU --------------------
// Structure FROZEN at the round-6 config (277-280 us, best of 7 variants:
// r0 290 / r1 320 / r3 315 / r5 372 / r7 491 / r9 357). Round-10 change is
// the A-staging SOURCE only: g_Q shift-table (1.2 MB, L2-hot) instead of the
// 42 MB g_A stream. Per-lane src: o=px+kw0, s=o&15 -> 16-aligned read of
// copy s at (o-s); content bit-identical to old g_A chunk. LDS layout,
// XOR swizzle, ds_reads, MFMA, epilogue byte-identical to r6.
__global__ __launch_bounds__(256, 4)
void gemm_scores()
{
    __shared__ char sA[128 * 128];   // 16 KB
    __shared__ char sB[128 * 128];   // 16 KB
    __shared__ float biasS[128];

    const int tid = threadIdx.x;
    const int b = blockIdx.x;
    const int nt = (b & 7) * 4 + ((b >> 3) & 3);   // 0..31
    const int lt = b >> 5;                          // 0..106
    const int l0 = lt * 128;
    const int n0 = nt * 128;

    if (tid < 128) biasS[tid] = g_bias[n0 + tid];

    const int wave = tid >> 6, lane = tid & 63;
    const int wy = wave >> 1, wx = wave & 1;      // wave tile: 64l x 64n
    const int mrow = lane & 15, kgrp = lane >> 4;

    intx4 acc[4][4];
    #pragma unroll
    for (int i = 0; i < 4; i++)
        #pragma unroll
        for (int j = 0; j < 4; j++) acc[i][j] = (intx4){0, 0, 0, 0};

    const char* Bb = g_B + (size_t)n0 * D_;

    // per-t A-chunk invariants: chunk c=tid+256t -> row=c>>3, jj=(c&7)^(row&7);
    // patch (py,px) of row l0+row (pad rows l>=L_ read dont-care data; their
    // candidate lists are never consumed — same as old zero-filled g_A rows).
    int jjA[4], pyA[4], pxA[4];
    #pragma unroll
    for (int t = 0; t < 4; t++) {
        int c = tid + 256 * t;
        int row = c >> 3;
        jjA[t] = (c & 7) ^ (row & 7);
        int l = l0 + row;
        pyA[t] = l / LWID;
        pxA[t] = l - pyA[t] * LWID;
    }

    for (int d0 = 0; d0 < D_; d0 += 128) {
        __syncthreads();
        // A from g_Q: element d = d0+jj*16 -> cch=d>>10, kh=(d>>5)&31, kw0=d&31
        #pragma unroll
        for (int t = 0; t < 4; t++) {
            int c = tid + 256 * t;
            int dA = d0 + jjA[t] * 16;
            int cch = dA >> 10;
            int kh = (dA >> 5) & 31;
            int kw0 = dA & 31;
            int y = pyA[t] + kh;
            int o = pxA[t] + kw0;
            int s = o & 15;
            const char* src = g_Q + (size_t)((s * 3 + cch) * QROWS + y) * QSTR + (o - s);
            gl_lds16(src, &sA[c * 16]);
        }
        // B from g_B (unchanged)
        #pragma unroll
        for (int t = 0; t < 4; t++) {
            int c = tid + 256 * t;
            int row = c >> 3;
            int jj = (c & 7) ^ (row & 7);
            gl_lds16(Bb + (size_t)row * D_ + d0 + jj * 16, &sB[c * 16]);
        }
        __syncthreads();

        #pragma unroll
        for (int ks = 0; ks < 2; ks++) {
            intx4 a[4], bf[4];
            #pragma unroll
            for (int i = 0; i < 4; i++) {
                int ra = wy * 64 + i * 16 + mrow;
                int ca = ra * 8 + ((ks * 4 + kgrp) ^ (ra & 7));
                a[i] = *(const intx4*)&sA[ca * 16];
            }
            #pragma unroll
            for (int j = 0; j < 4; j++) {
                int rb = wx * 64 + j * 16 + mrow;
                int cb = rb * 8 + ((ks * 4 + kgrp) ^ (rb & 7));
                bf[j] = *(const intx4*)&sB[cb * 16];
            }
            #pragma unroll
            for (int i = 0; i < 4; i++)
                #pragma unroll
                for (int j = 0; j < 4; j++)
                    acc[i][j] = __builtin_amdgcn_mfma_i32_16x16x64_i8(a[i], bf[j], acc[i][j], 0, 0, 0);
        }
    }

    // epilogue. C/D layout: col = lane&15 (mrow), row = kgrp*4 + reg.
    // 16-lane group max covers this wave's full 64-col n-slice; threshold is
    // a per-slice lower bound of the row max (extra candidates are pruned in
    // reduce_rescue against the global row max — semantics unchanged).
    #pragma unroll
    for (int i = 0; i < 4; i++) {
        #pragma unroll
        for (int r = 0; r < 4; r++) {
            const int lrow = l0 + wy * 64 + i * 16 + kgrp * 4 + r;
            float sc[4];
            #pragma unroll
            for (int j = 0; j < 4; j++)
                sc[j] = (float)acc[i][j][r] * INVS + biasS[wx * 64 + j * 16 + mrow];
            float bestv = sc[0]; int bestj = 0;
            #pragma unroll
            for (int j = 1; j < 4; j++)
                if (sc[j] > bestv) { bestv = sc[j]; bestj = j; }
            unsigned long long key = packkey(bestv, n0 + wx * 64 + bestj * 16 + mrow);
            #pragma unroll
            for (int m = 1; m < 16; m <<= 1) {
                unsigned long long o = __shfl_xor(key, m, 64);
                if (o > key) key = o;
            }
            float thr = unsortable((unsigned)(key >> 32)) - T_MARGIN;
            #pragma unroll
            for (int j = 0; j < 4; j++) {
                if (sc[j] >= thr) {
                    int pos = atomicAdd(&g_cnt[lrow], 1);
                    if (pos < CAP_)
                        g_list[(size_t)lrow * CAP_ + pos] =
                            packkey(sc[j], n0 + wx * 64 + j * 16 + mrow);
                }
            }
        }
    }
}

// ---- per-row shortlist + exact fp32 rescore + pattern resolve ---------------
// kk==1 early exit (r4, bit-identical); patch staged to LDS once; one wave
// per candidate, coalesced float4 dot, barrier-free loop (r8).
__global__ __launch_bounds__(256)
void reduce_rescue(const float* __restrict__ img, const float* __restrict__ mem,
                   const int* __restrict__ mapping)
{
    const int l = blockIdx.x;
    const int tid = threadIdx.x;
    const int lane = tid & 63, wave = tid >> 6;

    __shared__ unsigned long long redk[4];
    __shared__ int   scand[SCAP_];
    __shared__ int   scnt;
    __shared__ float patch[D_];            // 12 KB staged fp32 patch

    if (tid == 0) scnt = 0;
    int cnt = g_cnt[l];
    bool full = cnt > CAP_;
    __syncthreads();

    if (!full) {
        int k = cnt;
        const unsigned long long* lst = g_list + (size_t)l * CAP_;
        unsigned long long mk = 0ull;
        for (int q = tid; q < k; q += 256) {
            unsigned long long e = lst[q];
            if (e > mk) mk = e;
        }
        #pragma unroll
        for (int m = 32; m >= 1; m >>= 1) {
            unsigned long long o = __shfl_xor(mk, m, 64);
            if (o > mk) mk = o;
        }
        if (lane == 0) redk[wave] = mk;
        __syncthreads();
        unsigned long long rowk = redk[0];
        #pragma unroll
        for (int w = 1; w < 4; w++) if (redk[w] > rowk) rowk = redk[w];
        float thr = unsortable((unsigned)(rowk >> 32)) - T_MARGIN;
        for (int q = tid; q < k; q += 256) {
            unsigned long long e = lst[q];
            if (unsortable((unsigned)(e >> 32)) >= thr) {
                int p = atomicAdd(&scnt, 1);
                if (p < SCAP_) scand[p] = (int)(~(unsigned)(e & 0xFFFFFFFFull));
            }
        }
    }
    __syncthreads();
    bool scanall = full || (scnt > SCAP_);
    int kk = scanall ? NMEM_ : scnt;

    // early exit: a single shortlist candidate IS the argmax (exact semantics)
    if (!scanall && kk == 1) {
        if (tid == 0) { int n = scand[0]; g_best[l] = n; g_pat[l] = mapping[n]; }
        return;
    }

    // stage fp32 patch once (torch-unfold order: d = c*1024 + kh*32 + kw)
    const int py = l / LWID, px = l - (l / LWID) * LWID;
    for (int d = tid; d < D_; d += 256) {
        int c = d >> 10, rem = d & 1023, kh = rem >> 5, kw = rem & 31;
        int y = py + kh - PAD_, x = px + kw - PAD_;
        patch[d] = ((unsigned)y < (unsigned)H_ && (unsigned)x < (unsigned)W_)
                   ? img[((size_t)y * W_ + x) * C_ + c] : 0.f;
    }
    __syncthreads();

    // wave-per-candidate exact fp32 rescore, barrier-free loop
    const float4* pp = (const float4*)patch;
    unsigned long long bk = 0ull;
    for (int q = wave; q < kk; q += 4) {
        int n = scanall ? q : scand[q];
        const float4* mr = (const float4*)(mem + (size_t)n * D_);
        float s = 0.f;
        #pragma unroll
        for (int i = 0; i < 12; i++) {
            float4 m4 = mr[i * 64 + lane];
            float4 p4 = pp[i * 64 + lane];
            s = fmaf(m4.x, p4.x, s); s = fmaf(m4.y, p4.y, s);
            s = fmaf(m4.z, p4.z, s); s = fmaf(m4.w, p4.w, s);
        }
        #pragma unroll
        for (int sh = 32; sh >= 1; sh >>= 1) s += __shfl_xor(s, sh, 64);
        unsigned long long key = packkey(s + g_bias[n], n);
        if (key > bk) bk = key;
    }
    if (lane == 0) redk[wave] = bk;
    __syncthreads();
    if (tid == 0) {
        unsigned long long best = redk[0];
        #pragma unroll
        for (int w = 1; w < 4; w++) if (redk[w] > best) best = redk[w];
        int n = (int)(~(unsigned)(best & 0xFFFFFFFFull));
        g_best[l] = n; g_pat[l] = mapping[n];
    }
}

// ---- gather-fold: coalesced, py-quartered for parallelism -------------------
__global__ __launch_bounds__(128)
void gather_fold(const float* __restrict__ mem2)
{
    const int y = blockIdx.x;
    const int c = blockIdx.y;
    const int q = blockIdx.z;
    const int x = threadIdx.x;            // 0..127
    const int wv = x >> 6;

    const int py_lo = max(0, y - 21);
    const int py_hi = min(LWID - 1, y + PAD_);
    const int p0 = py_lo + q * 8;
    const int p1 = min(p0 + 8, py_hi + 1);
    const int nrows = (p1 > p0) ? (p1 - p0) : 0;

    __shared__ int patS[8 * LWID];
    for (int i = x; i < nrows * LWID; i += 128) {
        int rr = i / LWID, cc = i - rr * LWID;
        patS[i] = g_pat[(p0 + rr) * LWID + cc];
    }
    __syncthreads();

    const int slo = wv ? 43 : 0;
    const int shi = wv ? 116 : 73;

    float acc = 0.f;
    for (int py = p0; py < p1; ++py) {
        const int kh = y + PAD_ - py;                 // 0..31
        const int dbase = c * 1024 + kh * 32;
        const int* prow = &patS[(py - p0) * LWID];
        for (int s = slo; s <= shi; ++s) {
            int d = x + PAD_ - s;                     // lane-linear
            if ((unsigned)d < 32u)
                acc += mem2[(size_t)prow[s] * D_ + dbase + d];
        }
    }
    g_part[q][((size_t)y * W_ + x) * C_ + c] = acc;
}

// ---- sum partials + global max ----------------------------------------------
__global__ __launch_bounds__(256)
void maxfind(float* __restrict__ out)
{
    int i = blockIdx.x * 256 + threadIdx.x;           // 192*256 == 49152 exact
    float v = g_part[0][i] + g_part[1][i] + g_part[2][i] + g_part[3][i];
    out[i] = v;
    float m = v;
    #pragma unroll
    for (int s = 32; s >= 1; s >>= 1) m = fmaxf(m, __shfl_xor(m, s, 64));
    if ((threadIdx.x & 63) == 0) atomicMax(&g_max, sortable(m));
}

__global__ __launch_bounds__(256)
void normalize_k(float* __restrict__ out)
{
    int i = blockIdx.x * 256 + threadIdx.x;
    float mx = unsortable(g_max);
    out[i] = out[i] / mx;
}

extern "C" void kernel_launch(void* const* d_in, const int* in_sizes, int n_in,
                              void* d_out, int out_size, void* d_ws, size_t ws_size,
                              hipStream_t stream)
{
    const float* img     = (const float*)d_in[0];   // (128,128,3)
    const float* mem     = (const float*)d_in[1];   // (4096,3072)
    const float* mem2    = (const float*)d_in[2];   // (4096,3072)
    const int*   mapping = (const int*)d_in[3];     // (4096,)
    float* out = (float*)d_out;                     // (128,128,3)

    prep<<<NMEM_ + 16 * 3 * QROWS, 256, 0, stream>>>(img, mem);
    gemm_scores<<<(NMEM_ / 128) * (LPAD / 128), 256, 0, stream>>>();
    reduce_rescue<<<L_, 256, 0, stream>>>(img, mem, mapping);
    gather_fold<<<dim3(H_, C_, 4), 128, 0, stream>>>(mem2);
    maxfind<<<192, 256, 0, stream>>>(out);
    normalize_k<<<192, 256, 0, stream>>>(out);
}

// Round 11
// 467.037 us; speedup vs baseline: 1.3098x; 1.0180x over previous
//
#include <hip/hip_runtime.h>

// Problem constants
#define H_    128
#define W_    128
#define C_    3
#define PAD_  10
#define LWID  117          // LW = LH = 117
#define L_    13689        // LH*LW
#define LPAD  13696        // 107 * 128
#define D_    3072         // C*KH*KW
#define NMEM_ 4096

#define T_MARGIN 3.0f      // candidate margin; i8-quant score err sigma ~0.32 (9 sigma)
#define CAP_     256       // per-row candidate list capacity
#define SCAP_    64        // rescue shortlist capacity (expected ~1.4)

#define PSCALE 127.0f      // patch quant scale (p in [0,1))
#define MSCALE 32.0f       // mem quant scale (clip +-3.97)
#define INVS   (1.0f / (PSCALE * MSCALE))

// shifted quantized-image table: g_Q[s][c][y][j] = qimg[c][y][j+s]
// (y,j in padded coords, row stride 160, 160 rows; 16 shift copies so any
// 16B window (px+kw0) is a 16-aligned load from copy s=(px+kw0)&15)
#define QROWS 160
#define QSTR  160
#define QPLANE (QROWS * QSTR)          // 25600 per (s,c)

typedef int   intx4  __attribute__((ext_vector_type(4)));

// Static device-side scratch (bss) — no d_ws dependency
__device__ int                g_best[L_];
__device__ int                g_pat[L_];     // mapping[g_best[l]] resolved in rescue
__device__ float              g_bias[NMEM_];
__device__ unsigned           g_max;
__device__ int                g_cnt[LPAD];
__device__ unsigned long long g_list[(size_t)LPAD * CAP_];   // 28 MB
__device__ __align__(16) char g_Q[16 * 3 * QPLANE];          // 1.23 MB
__device__ char               g_B[(size_t)NMEM_ * D_];       // 12.6 MB i8 mem
__device__ float              g_part[4][H_ * W_ * C_];       // fold partials, 786 KB

__device__ __forceinline__ unsigned sortable(float f) {
    unsigned b = __float_as_uint(f);
    return (b & 0x80000000u) ? ~b : (b | 0x80000000u);
}
__device__ __forceinline__ float unsortable(unsigned u) {
    unsigned b = (u & 0x80000000u) ? (u & 0x7FFFFFFFu) : ~u;
    return __uint_as_float(b);
}
__device__ __forceinline__ unsigned long long packkey(float s, int n) {
    // max-key == max score; ties -> smaller n (jnp.argmax first-index)
    return ((unsigned long long)sortable(s) << 32) | (unsigned)(~n);
}

// async global->LDS, 16 bytes per lane (global_load_lds_dwordx4)
__device__ __forceinline__ void gl_lds16(const char* g, char* l) {
    __builtin_amdgcn_global_load_lds(
        (const __attribute__((address_space(1))) unsigned int*)(g),
        (__attribute__((address_space(3))) unsigned int*)(l), 16, 0, 0);
}

__device__ __forceinline__ int pack4(int a, int b, int c, int d) {
    return (a & 255) | ((b & 255) << 8) | ((c & 255) << 16) | ((d & 255) << 24);
}

// ---- fused prep: quantize mem + bias | build g_Q shift table | zero cnts ----
// (round-10 structure, verified): A[l][d] = qimg[c][py+kh][px+kw] is staged
// straight from the 1.2 MB g_Q shift table; no 42 MB g_A materialization.
__global__ __launch_bounds__(256)
void prep(const float* __restrict__ img, const float* __restrict__ mem)
{
    const int b = blockIdx.x;
    if (b < NMEM_) {
        const int n = b;
        const float4* row = (const float4*)(mem + (size_t)n * D_);
        int* q8 = (int*)(g_B + (size_t)n * D_);
        float s = 0.f;
        for (int q = threadIdx.x; q < D_ / 4; q += 256) {
            float4 v = row[q];
            int q0 = __float2int_rn(fminf(fmaxf(v.x * MSCALE, -127.f), 127.f));
            int q1 = __float2int_rn(fminf(fmaxf(v.y * MSCALE, -127.f), 127.f));
            int q2 = __float2int_rn(fminf(fmaxf(v.z * MSCALE, -127.f), 127.f));
            int q3 = __float2int_rn(fminf(fmaxf(v.w * MSCALE, -127.f), 127.f));
            q8[q] = pack4(q0, q1, q2, q3);
            s = fmaf(v.x, v.x, s); s = fmaf(v.y, v.y, s);
            s = fmaf(v.z, v.z, s); s = fmaf(v.w, v.w, s);
        }
        #pragma unroll
        for (int m = 32; m >= 1; m >>= 1) s += __shfl_down(s, m, 64);
        __shared__ float red[4];
        int lane = threadIdx.x & 63, w = threadIdx.x >> 6;
        if (lane == 0) red[w] = s;
        __syncthreads();
        if (threadIdx.x == 0) g_bias[n] = -0.5f * (red[0] + red[1] + red[2] + red[3]);
    } else {
        const int bb = b - NMEM_;              // 0..7679 = (s,c,y)
        const int tid = threadIdx.x;
        // zero candidate counters (7680*256 covers LPAD)
        int g = bb * 256 + tid;
        if (g < LPAD) g_cnt[g] = 0;
        if (g == 0) g_max = 0u;
        // build one shift-table row
        const int sft = bb / (3 * QROWS);
        const int rem = bb - sft * (3 * QROWS);
        const int c = rem / QROWS;
        const int y = rem - c * QROWS;
        if (tid < QSTR) {
            const int yy = y - PAD_;
            const int x = tid + sft - PAD_;
            char v = 0;
            if ((unsigned)yy < (unsigned)H_ && (unsigned)x < (unsigned)W_)
                v = (char)__float2int_rn(img[((size_t)yy * W_ + x) * C_ + c] * PSCALE);
            g_Q[(size_t)((sft * 3 + c) * QROWS + y) * QSTR + tid] = v;
        }
    }
}

// ---- i8 MFMA GEMM, 128l x 128n tile, BK=128, ~3-4 blocks/CU -----------------
// Structure frozen at r6 config; A-source = g_Q shift table (r10, verified).
// Round-11: incremental A-offsets. r10's per-step A-address recompute cost
// +8 pts VALUBusy (r6 20.6 -> r10 28.7). The source address is affine in the
// K-step: +4 image rows = +640 B/step within a c-block; at c-block boundaries
// (d0&1023 == 896) the delta is +25600 (plane) - 4480 (kh wraps -28 rows)
// + 640 = +21120 B — uniform over chunks/lanes, scalar-selectable. One u32
// offset per chunk replaces the whole recompute (B path already
// strength-reduced by the compiler; left as-is).
__global__ __launch_bounds__(256, 4)
void gemm_scores()
{
    __shared__ char sA[128 * 128];   // 16 KB
    __shared__ char sB[128 * 128];   // 16 KB
    __shared__ float biasS[128];

    const int tid = threadIdx.x;
    const int b = blockIdx.x;
    const int nt = (b & 7) * 4 + ((b >> 3) & 3);   // 0..31
    const int lt = b >> 5;                          // 0..106
    const int l0 = lt * 128;
    const int n0 = nt * 128;

    if (tid < 128) biasS[tid] = g_bias[n0 + tid];

    const int wave = tid >> 6, lane = tid & 63;
    const int wy = wave >> 1, wx = wave & 1;      // wave tile: 64l x 64n
    const int mrow = lane & 15, kgrp = lane >> 4;

    intx4 acc[4][4];
    #pragma unroll
    for (int i = 0; i < 4; i++)
        #pragma unroll
        for (int j = 0; j < 4; j++) acc[i][j] = (intx4){0, 0, 0, 0};

    const char* Bb = g_B + (size_t)n0 * D_;

    // per-chunk initial A offset into g_Q (at d0=0: cch=0, kh=dA>>5, kw0=dA&31
    // with dA = jj*16 < 128), then advance incrementally per K-step.
    unsigned offA[4];
    #pragma unroll
    for (int t = 0; t < 4; t++) {
        int c = tid + 256 * t;
        int row = c >> 3;
        int jj = (c & 7) ^ (row & 7);
        int l = l0 + row;
        int py = l / LWID, px = l - py * LWID;
        int dA = jj * 16;
        int kh = dA >> 5;              // 0..3
        int kw0 = dA & 31;             // 0 or 16
        int o = px + kw0;
        int s = o & 15;
        offA[t] = (unsigned)(((s * 3) * QROWS + (py + kh)) * QSTR + (o - s));
    }

    for (int d0 = 0; d0 < D_; d0 += 128) {
        __syncthreads();
        // A from g_Q via incremental offsets (16-aligned by construction)
        #pragma unroll
        for (int t = 0; t < 4; t++)
            gl_lds16(g_Q + offA[t], &sA[(tid + 256 * t) * 16]);
        // B from g_B (compiler strength-reduces d0)
        #pragma unroll
        for (int t = 0; t < 4; t++) {
            int c = tid + 256 * t;
            int row = c >> 3;
            int jj = (c & 7) ^ (row & 7);
            gl_lds16(Bb + (size_t)row * D_ + d0 + jj * 16, &sB[c * 16]);
        }
        // advance A offsets: uniform scalar select (640 in-block, 21120 at
        // the c-block boundary step d0 = 1024k + 896)
        const unsigned stepA = ((d0 & 1023) == 896) ? 21120u : 640u;
        #pragma unroll
        for (int t = 0; t < 4; t++) offA[t] += stepA;
        __syncthreads();

        #pragma unroll
        for (int ks = 0; ks < 2; ks++) {
            intx4 a[4], bf[4];
            #pragma unroll
            for (int i = 0; i < 4; i++) {
                int ra = wy * 64 + i * 16 + mrow;
                int ca = ra * 8 + ((ks * 4 + kgrp) ^ (ra & 7));
                a[i] = *(const intx4*)&sA[ca * 16];
            }
            #pragma unroll
            for (int j = 0; j < 4; j++) {
                int rb = wx * 64 + j * 16 + mrow;
                int cb = rb * 8 + ((ks * 4 + kgrp) ^ (rb & 7));
                bf[j] = *(const intx4*)&sB[cb * 16];
            }
            #pragma unroll
            for (int i = 0; i < 4; i++)
                #pragma unroll
                for (int j = 0; j < 4; j++)
                    acc[i][j] = __builtin_amdgcn_mfma_i32_16x16x64_i8(a[i], bf[j], acc[i][j], 0, 0, 0);
        }
    }

    // epilogue. C/D layout: col = lane&15 (mrow), row = kgrp*4 + reg.
    // 16-lane group max covers this wave's full 64-col n-slice; threshold is
    // a per-slice lower bound of the row max (extra candidates are pruned in
    // reduce_rescue against the global row max — semantics unchanged).
    #pragma unroll
    for (int i = 0; i < 4; i++) {
        #pragma unroll
        for (int r = 0; r < 4; r++) {
            const int lrow = l0 + wy * 64 + i * 16 + kgrp * 4 + r;
            float sc[4];
            #pragma unroll
            for (int j = 0; j < 4; j++)
                sc[j] = (float)acc[i][j][r] * INVS + biasS[wx * 64 + j * 16 + mrow];
            float bestv = sc[0]; int bestj = 0;
            #pragma unroll
            for (int j = 1; j < 4; j++)
                if (sc[j] > bestv) { bestv = sc[j]; bestj = j; }
            unsigned long long key = packkey(bestv, n0 + wx * 64 + bestj * 16 + mrow);
            #pragma unroll
            for (int m = 1; m < 16; m <<= 1) {
                unsigned long long o = __shfl_xor(key, m, 64);
                if (o > key) key = o;
            }
            float thr = unsortable((unsigned)(key >> 32)) - T_MARGIN;
            #pragma unroll
            for (int j = 0; j < 4; j++) {
                if (sc[j] >= thr) {
                    int pos = atomicAdd(&g_cnt[lrow], 1);
                    if (pos < CAP_)
                        g_list[(size_t)lrow * CAP_ + pos] =
                            packkey(sc[j], n0 + wx * 64 + j * 16 + mrow);
                }
            }
        }
    }
}

// ---- per-row shortlist + exact fp32 rescore + pattern resolve ---------------
// kk==1 early exit (r4, bit-identical); patch staged to LDS once; one wave
// per candidate, coalesced float4 dot, barrier-free loop (r8).
__global__ __launch_bounds__(256)
void reduce_rescue(const float* __restrict__ img, const float* __restrict__ mem,
                   const int* __restrict__ mapping)
{
    const int l = blockIdx.x;
    const int tid = threadIdx.x;
    const int lane = tid & 63, wave = tid >> 6;

    __shared__ unsigned long long redk[4];
    __shared__ int   scand[SCAP_];
    __shared__ int   scnt;
    __shared__ float patch[D_];            // 12 KB staged fp32 patch

    if (tid == 0) scnt = 0;
    int cnt = g_cnt[l];
    bool full = cnt > CAP_;
    __syncthreads();

    if (!full) {
        int k = cnt;
        const unsigned long long* lst = g_list + (size_t)l * CAP_;
        unsigned long long mk = 0ull;
        for (int q = tid; q < k; q += 256) {
            unsigned long long e = lst[q];
            if (e > mk) mk = e;
        }
        #pragma unroll
        for (int m = 32; m >= 1; m >>= 1) {
            unsigned long long o = __shfl_xor(mk, m, 64);
            if (o > mk) mk = o;
        }
        if (lane == 0) redk[wave] = mk;
        __syncthreads();
        unsigned long long rowk = redk[0];
        #pragma unroll
        for (int w = 1; w < 4; w++) if (redk[w] > rowk) rowk = redk[w];
        float thr = unsortable((unsigned)(rowk >> 32)) - T_MARGIN;
        for (int q = tid; q < k; q += 256) {
            unsigned long long e = lst[q];
            if (unsortable((unsigned)(e >> 32)) >= thr) {
                int p = atomicAdd(&scnt, 1);
                if (p < SCAP_) scand[p] = (int)(~(unsigned)(e & 0xFFFFFFFFull));
            }
        }
    }
    __syncthreads();
    bool scanall = full || (scnt > SCAP_);
    int kk = scanall ? NMEM_ : scnt;

    // early exit: a single shortlist candidate IS the argmax (exact semantics)
    if (!scanall && kk == 1) {
        if (tid == 0) { int n = scand[0]; g_best[l] = n; g_pat[l] = mapping[n]; }
        return;
    }

    // stage fp32 patch once (torch-unfold order: d = c*1024 + kh*32 + kw)
    const int py = l / LWID, px = l - (l / LWID) * LWID;
    for (int d = tid; d < D_; d += 256) {
        int c = d >> 10, rem = d & 1023, kh = rem >> 5, kw = rem & 31;
        int y = py + kh - PAD_, x = px + kw - PAD_;
        patch[d] = ((unsigned)y < (unsigned)H_ && (unsigned)x < (unsigned)W_)
                   ? img[((size_t)y * W_ + x) * C_ + c] : 0.f;
    }
    __syncthreads();

    // wave-per-candidate exact fp32 rescore, barrier-free loop
    const float4* pp = (const float4*)patch;
    unsigned long long bk = 0ull;
    for (int q = wave; q < kk; q += 4) {
        int n = scanall ? q : scand[q];
        const float4* mr = (const float4*)(mem + (size_t)n * D_);
        float s = 0.f;
        #pragma unroll
        for (int i = 0; i < 12; i++) {
            float4 m4 = mr[i * 64 + lane];
            float4 p4 = pp[i * 64 + lane];
            s = fmaf(m4.x, p4.x, s); s = fmaf(m4.y, p4.y, s);
            s = fmaf(m4.z, p4.z, s); s = fmaf(m4.w, p4.w, s);
        }
        #pragma unroll
        for (int sh = 32; sh >= 1; sh >>= 1) s += __shfl_xor(s, sh, 64);
        unsigned long long key = packkey(s + g_bias[n], n);
        if (key > bk) bk = key;
    }
    if (lane == 0) redk[wave] = bk;
    __syncthreads();
    if (tid == 0) {
        unsigned long long best = redk[0];
        #pragma unroll
        for (int w = 1; w < 4; w++) if (redk[w] > best) best = redk[w];
        int n = (int)(~(unsigned)(best & 0xFFFFFFFFull));
        g_best[l] = n; g_pat[l] = mapping[n];
    }
}

// ---- gather-fold: coalesced, py-quartered for parallelism -------------------
__global__ __launch_bounds__(128)
void gather_fold(const float* __restrict__ mem2)
{
    const int y = blockIdx.x;
    const int c = blockIdx.y;
    const int q = blockIdx.z;
    const int x = threadIdx.x;            // 0..127
    const int wv = x >> 6;

    const int py_lo = max(0, y - 21);
    const int py_hi = min(LWID - 1, y + PAD_);
    const int p0 = py_lo + q * 8;
    const int p1 = min(p0 + 8, py_hi + 1);
    const int nrows = (p1 > p0) ? (p1 - p0) : 0;

    __shared__ int patS[8 * LWID];
    for (int i = x; i < nrows * LWID; i += 128) {
        int rr = i / LWID, cc = i - rr * LWID;
        patS[i] = g_pat[(p0 + rr) * LWID + cc];
    }
    __syncthreads();

    const int slo = wv ? 43 : 0;
    const int shi = wv ? 116 : 73;

    float acc = 0.f;
    for (int py = p0; py < p1; ++py) {
        const int kh = y + PAD_ - py;                 // 0..31
        const int dbase = c * 1024 + kh * 32;
        const int* prow = &patS[(py - p0) * LWID];
        for (int s = slo; s <= shi; ++s) {
            int d = x + PAD_ - s;                     // lane-linear
            if ((unsigned)d < 32u)
                acc += mem2[(size_t)prow[s] * D_ + dbase + d];
        }
    }
    g_part[q][((size_t)y * W_ + x) * C_ + c] = acc;
}

// ---- sum partials + global max ----------------------------------------------
__global__ __launch_bounds__(256)
void maxfind(float* __restrict__ out)
{
    int i = blockIdx.x * 256 + threadIdx.x;           // 192*256 == 49152 exact
    float v = g_part[0][i] + g_part[1][i] + g_part[2][i] + g_part[3][i];
    out[i] = v;
    float m = v;
    #pragma unroll
    for (int s = 32; s >= 1; s >>= 1) m = fmaxf(m, __shfl_xor(m, s, 64));
    if ((threadIdx.x & 63) == 0) atomicMax(&g_max, sortable(m));
}

__global__ __launch_bounds__(256)
void normalize_k(float* __restrict__ out)
{
    int i = blockIdx.x * 256 + threadIdx.x;
    float mx = unsortable(g_max);
    out[i] = out[i] / mx;
}

extern "C" void kernel_launch(void* const* d_in, const int* in_sizes, int n_in,
                              void* d_out, int out_size, void* d_ws, size_t ws_size,
                              hipStream_t stream)
{
    const float* img     = (const float*)d_in[0];   // (128,128,3)
    const float* mem     = (const float*)d_in[1];   // (4096,3072)
    const float* mem2    = (const float*)d_in[2];   // (4096,3072)
    const int*   mapping = (const int*)d_in[3];     // (4096,)
    float* out = (float*)d_out;                     // (128,128,3)

    prep<<<NMEM_ + 16 * 3 * QROWS, 256, 0, stream>>>(img, mem);
    gemm_scores<<<(NMEM_ / 128) * (LPAD / 128), 256, 0, stream>>>();
    reduce_rescue<<<L_, 256, 0, stream>>>(img, mem, mapping);
    gather_fold<<<dim3(H_, C_, 4), 128, 0, stream>>>(mem2);
    maxfind<<<192, 256, 0, stream>>>(out);
    normalize_k<<<192, 256, 0, stream>>>(out);
}

// Round 12
// 428.477 us; speedup vs baseline: 1.4276x; 1.0900x over previous
//
#include <hip/hip_runtime.h>

// Problem constants
#define H_    128
#define W_    128
#define C_    3
#define PAD_  10
#define LWID  117          // LW = LH = 117
#define L_    13689        // LH*LW
#define LPAD  13696        // 107 * 128
#define D_    3072         // C*KH*KW
#define NMEM_ 4096

#define T_MARGIN 3.0f      // candidate margin; i8-quant score err sigma ~0.32 (9 sigma)
#define CAP_     256       // per-row candidate list capacity
#define SCAP_    64        // rescue shortlist capacity (expected ~1.4)

#define PSCALE 127.0f      // patch quant scale (p in [0,1))
#define MSCALE 32.0f       // mem quant scale (clip +-3.97)
#define INVS   (1.0f / (PSCALE * MSCALE))

// shifted quantized-image table: g_Q[s][c][y][j] = qimg[c][y][j+s]
// (y,j in padded coords, row stride 160, 160 rows; 16 shift copies so any
// 16B window (px+kw0) is a 16-aligned load from copy s=(px+kw0)&15)
#define QROWS 160
#define QSTR  160
#define QPLANE (QROWS * QSTR)          // 25600 per (s,c)

typedef int   intx4  __attribute__((ext_vector_type(4)));

// Static device-side scratch (bss) — no d_ws dependency
__device__ int                g_best[L_];
__device__ int                g_pat[L_];     // mapping[g_best[l]] resolved in rescue
__device__ float              g_bias[NMEM_];
__device__ unsigned           g_max;
__device__ int                g_cnt[LPAD];
__device__ unsigned long long g_list[(size_t)LPAD * CAP_];   // 28 MB
__device__ __align__(16) char g_Q[16 * 3 * QPLANE];          // 1.23 MB
__device__ char               g_B[(size_t)NMEM_ * D_];       // 12.6 MB i8 mem
__device__ float              g_part[4][H_ * W_ * C_];       // fold partials, 786 KB

__device__ __forceinline__ unsigned sortable(float f) {
    unsigned b = __float_as_uint(f);
    return (b & 0x80000000u) ? ~b : (b | 0x80000000u);
}
__device__ __forceinline__ float unsortable(unsigned u) {
    unsigned b = (u & 0x80000000u) ? (u & 0x7FFFFFFFu) : ~u;
    return __uint_as_float(b);
}
__device__ __forceinline__ unsigned long long packkey(float s, int n) {
    // max-key == max score; ties -> smaller n (jnp.argmax first-index)
    return ((unsigned long long)sortable(s) << 32) | (unsigned)(~n);
}

// async global->LDS, 16 bytes per lane (global_load_lds_dwordx4)
__device__ __forceinline__ void gl_lds16(const char* g, char* l) {
    __builtin_amdgcn_global_load_lds(
        (const __attribute__((address_space(1))) unsigned int*)(g),
        (__attribute__((address_space(3))) unsigned int*)(l), 16, 0, 0);
}

__device__ __forceinline__ int pack4(int a, int b, int c, int d) {
    return (a & 255) | ((b & 255) << 8) | ((c & 255) << 16) | ((d & 255) << 24);
}

// ---- fused prep: quantize mem + bias | build g_Q shift table | zero cnts ----
// (round-10 structure, verified): A[l][d] = qimg[c][py+kh][px+kw] is staged
// straight from the 1.2 MB g_Q shift table; no 42 MB g_A materialization.
__global__ __launch_bounds__(256)
void prep(const float* __restrict__ img, const float* __restrict__ mem)
{
    const int b = blockIdx.x;
    if (b < NMEM_) {
        const int n = b;
        const float4* row = (const float4*)(mem + (size_t)n * D_);
        int* q8 = (int*)(g_B + (size_t)n * D_);
        float s = 0.f;
        for (int q = threadIdx.x; q < D_ / 4; q += 256) {
            float4 v = row[q];
            int q0 = __float2int_rn(fminf(fmaxf(v.x * MSCALE, -127.f), 127.f));
            int q1 = __float2int_rn(fminf(fmaxf(v.y * MSCALE, -127.f), 127.f));
            int q2 = __float2int_rn(fminf(fmaxf(v.z * MSCALE, -127.f), 127.f));
            int q3 = __float2int_rn(fminf(fmaxf(v.w * MSCALE, -127.f), 127.f));
            q8[q] = pack4(q0, q1, q2, q3);
            s = fmaf(v.x, v.x, s); s = fmaf(v.y, v.y, s);
            s = fmaf(v.z, v.z, s); s = fmaf(v.w, v.w, s);
        }
        #pragma unroll
        for (int m = 32; m >= 1; m >>= 1) s += __shfl_down(s, m, 64);
        __shared__ float red[4];
        int lane = threadIdx.x & 63, w = threadIdx.x >> 6;
        if (lane == 0) red[w] = s;
        __syncthreads();
        if (threadIdx.x == 0) g_bias[n] = -0.5f * (red[0] + red[1] + red[2] + red[3]);
    } else {
        const int bb = b - NMEM_;              // 0..7679 = (s,c,y)
        const int tid = threadIdx.x;
        // zero candidate counters (7680*256 covers LPAD)
        int g = bb * 256 + tid;
        if (g < LPAD) g_cnt[g] = 0;
        if (g == 0) g_max = 0u;
        // build one shift-table row
        const int sft = bb / (3 * QROWS);
        const int rem = bb - sft * (3 * QROWS);
        const int c = rem / QROWS;
        const int y = rem - c * QROWS;
        if (tid < QSTR) {
            const int yy = y - PAD_;
            const int x = tid + sft - PAD_;
            char v = 0;
            if ((unsigned)yy < (unsigned)H_ && (unsigned)x < (unsigned)W_)
                v = (char)__float2int_rn(img[((size_t)yy * W_ + x) * C_ + c] * PSCALE);
            g_Q[(size_t)((sft * 3 + c) * QROWS + y) * QSTR + tid] = v;
        }
    }
}

// ---- i8 MFMA GEMM, 128l x 128n tile, BK=128, ~3-4 blocks/CU -----------------
// Structure frozen at r6 config; A-source = g_Q shift table (r10) + r11
// incremental A-offsets (VALUBusy 28.7 -> 23.7, 259 -> 250 us). Plateaued:
// occupancy and A-dematerialization paid; 5 scheduling/config variants null
// or worse. Leave untouched.
__global__ __launch_bounds__(256, 4)
void gemm_scores()
{
    __shared__ char sA[128 * 128];   // 16 KB
    __shared__ char sB[128 * 128];   // 16 KB
    __shared__ float biasS[128];

    const int tid = threadIdx.x;
    const int b = blockIdx.x;
    const int nt = (b & 7) * 4 + ((b >> 3) & 3);   // 0..31
    const int lt = b >> 5;                          // 0..106
    const int l0 = lt * 128;
    const int n0 = nt * 128;

    if (tid < 128) biasS[tid] = g_bias[n0 + tid];

    const int wave = tid >> 6, lane = tid & 63;
    const int wy = wave >> 1, wx = wave & 1;      // wave tile: 64l x 64n
    const int mrow = lane & 15, kgrp = lane >> 4;

    intx4 acc[4][4];
    #pragma unroll
    for (int i = 0; i < 4; i++)
        #pragma unroll
        for (int j = 0; j < 4; j++) acc[i][j] = (intx4){0, 0, 0, 0};

    const char* Bb = g_B + (size_t)n0 * D_;

    // per-chunk initial A offset into g_Q (at d0=0: cch=0, kh=dA>>5, kw0=dA&31
    // with dA = jj*16 < 128), then advance incrementally per K-step.
    unsigned offA[4];
    #pragma unroll
    for (int t = 0; t < 4; t++) {
        int c = tid + 256 * t;
        int row = c >> 3;
        int jj = (c & 7) ^ (row & 7);
        int l = l0 + row;
        int py = l / LWID, px = l - py * LWID;
        int dA = jj * 16;
        int kh = dA >> 5;              // 0..3
        int kw0 = dA & 31;             // 0 or 16
        int o = px + kw0;
        int s = o & 15;
        offA[t] = (unsigned)(((s * 3) * QROWS + (py + kh)) * QSTR + (o - s));
    }

    for (int d0 = 0; d0 < D_; d0 += 128) {
        __syncthreads();
        // A from g_Q via incremental offsets (16-aligned by construction)
        #pragma unroll
        for (int t = 0; t < 4; t++)
            gl_lds16(g_Q + offA[t], &sA[(tid + 256 * t) * 16]);
        // B from g_B (compiler strength-reduces d0)
        #pragma unroll
        for (int t = 0; t < 4; t++) {
            int c = tid + 256 * t;
            int row = c >> 3;
            int jj = (c & 7) ^ (row & 7);
            gl_lds16(Bb + (size_t)row * D_ + d0 + jj * 16, &sB[c * 16]);
        }
        // advance A offsets: uniform scalar select (640 in-block, 21120 at
        // the c-block boundary step d0 = 1024k + 896)
        const unsigned stepA = ((d0 & 1023) == 896) ? 21120u : 640u;
        #pragma unroll
        for (int t = 0; t < 4; t++) offA[t] += stepA;
        __syncthreads();

        #pragma unroll
        for (int ks = 0; ks < 2; ks++) {
            intx4 a[4], bf[4];
            #pragma unroll
            for (int i = 0; i < 4; i++) {
                int ra = wy * 64 + i * 16 + mrow;
                int ca = ra * 8 + ((ks * 4 + kgrp) ^ (ra & 7));
                a[i] = *(const intx4*)&sA[ca * 16];
            }
            #pragma unroll
            for (int j = 0; j < 4; j++) {
                int rb = wx * 64 + j * 16 + mrow;
                int cb = rb * 8 + ((ks * 4 + kgrp) ^ (rb & 7));
                bf[j] = *(const intx4*)&sB[cb * 16];
            }
            #pragma unroll
            for (int i = 0; i < 4; i++)
                #pragma unroll
                for (int j = 0; j < 4; j++)
                    acc[i][j] = __builtin_amdgcn_mfma_i32_16x16x64_i8(a[i], bf[j], acc[i][j], 0, 0, 0);
        }
    }

    // epilogue. C/D layout: col = lane&15 (mrow), row = kgrp*4 + reg.
    // 16-lane group max covers this wave's full 64-col n-slice; threshold is
    // a per-slice lower bound of the row max (extra candidates are pruned in
    // reduce_rescue against the global row max — semantics unchanged).
    #pragma unroll
    for (int i = 0; i < 4; i++) {
        #pragma unroll
        for (int r = 0; r < 4; r++) {
            const int lrow = l0 + wy * 64 + i * 16 + kgrp * 4 + r;
            float sc[4];
            #pragma unroll
            for (int j = 0; j < 4; j++)
                sc[j] = (float)acc[i][j][r] * INVS + biasS[wx * 64 + j * 16 + mrow];
            float bestv = sc[0]; int bestj = 0;
            #pragma unroll
            for (int j = 1; j < 4; j++)
                if (sc[j] > bestv) { bestv = sc[j]; bestj = j; }
            unsigned long long key = packkey(bestv, n0 + wx * 64 + bestj * 16 + mrow);
            #pragma unroll
            for (int m = 1; m < 16; m <<= 1) {
                unsigned long long o = __shfl_xor(key, m, 64);
                if (o > key) key = o;
            }
            float thr = unsortable((unsigned)(key >> 32)) - T_MARGIN;
            #pragma unroll
            for (int j = 0; j < 4; j++) {
                if (sc[j] >= thr) {
                    int pos = atomicAdd(&g_cnt[lrow], 1);
                    if (pos < CAP_)
                        g_list[(size_t)lrow * CAP_ + pos] =
                            packkey(sc[j], n0 + wx * 64 + j * 16 + mrow);
                }
            }
        }
    }
}

// ---- per-row shortlist + exact fp32 rescore + pattern resolve ---------------
// kk==1 early exit (r4, bit-identical); patch staged to LDS once; one wave
// per candidate, coalesced float4 dot, barrier-free loop (r8).
__global__ __launch_bounds__(256)
void reduce_rescue(const float* __restrict__ img, const float* __restrict__ mem,
                   const int* __restrict__ mapping)
{
    const int l = blockIdx.x;
    const int tid = threadIdx.x;
    const int lane = tid & 63, wave = tid >> 6;

    __shared__ unsigned long long redk[4];
    __shared__ int   scand[SCAP_];
    __shared__ int   scnt;
    __shared__ float patch[D_];            // 12 KB staged fp32 patch

    if (tid == 0) scnt = 0;
    int cnt = g_cnt[l];
    bool full = cnt > CAP_;
    __syncthreads();

    if (!full) {
        int k = cnt;
        const unsigned long long* lst = g_list + (size_t)l * CAP_;
        unsigned long long mk = 0ull;
        for (int q = tid; q < k; q += 256) {
            unsigned long long e = lst[q];
            if (e > mk) mk = e;
        }
        #pragma unroll
        for (int m = 32; m >= 1; m >>= 1) {
            unsigned long long o = __shfl_xor(mk, m, 64);
            if (o > mk) mk = o;
        }
        if (lane == 0) redk[wave] = mk;
        __syncthreads();
        unsigned long long rowk = redk[0];
        #pragma unroll
        for (int w = 1; w < 4; w++) if (redk[w] > rowk) rowk = redk[w];
        float thr = unsortable((unsigned)(rowk >> 32)) - T_MARGIN;
        for (int q = tid; q < k; q += 256) {
            unsigned long long e = lst[q];
            if (unsortable((unsigned)(e >> 32)) >= thr) {
                int p = atomicAdd(&scnt, 1);
                if (p < SCAP_) scand[p] = (int)(~(unsigned)(e & 0xFFFFFFFFull));
            }
        }
    }
    __syncthreads();
    bool scanall = full || (scnt > SCAP_);
    int kk = scanall ? NMEM_ : scnt;

    // early exit: a single shortlist candidate IS the argmax (exact semantics)
    if (!scanall && kk == 1) {
        if (tid == 0) { int n = scand[0]; g_best[l] = n; g_pat[l] = mapping[n]; }
        return;
    }

    // stage fp32 patch once (torch-unfold order: d = c*1024 + kh*32 + kw)
    const int py = l / LWID, px = l - (l / LWID) * LWID;
    for (int d = tid; d < D_; d += 256) {
        int c = d >> 10, rem = d & 1023, kh = rem >> 5, kw = rem & 31;
        int y = py + kh - PAD_, x = px + kw - PAD_;
        patch[d] = ((unsigned)y < (unsigned)H_ && (unsigned)x < (unsigned)W_)
                   ? img[((size_t)y * W_ + x) * C_ + c] : 0.f;
    }
    __syncthreads();

    // wave-per-candidate exact fp32 rescore, barrier-free loop
    const float4* pp = (const float4*)patch;
    unsigned long long bk = 0ull;
    for (int q = wave; q < kk; q += 4) {
        int n = scanall ? q : scand[q];
        const float4* mr = (const float4*)(mem + (size_t)n * D_);
        float s = 0.f;
        #pragma unroll
        for (int i = 0; i < 12; i++) {
            float4 m4 = mr[i * 64 + lane];
            float4 p4 = pp[i * 64 + lane];
            s = fmaf(m4.x, p4.x, s); s = fmaf(m4.y, p4.y, s);
            s = fmaf(m4.z, p4.z, s); s = fmaf(m4.w, p4.w, s);
        }
        #pragma unroll
        for (int sh = 32; sh >= 1; sh >>= 1) s += __shfl_xor(s, sh, 64);
        unsigned long long key = packkey(s + g_bias[n], n);
        if (key > bk) bk = key;
    }
    if (lane == 0) redk[wave] = bk;
    __syncthreads();
    if (tid == 0) {
        unsigned long long best = redk[0];
        #pragma unroll
        for (int w = 1; w < 4; w++) if (redk[w] > best) best = redk[w];
        int n = (int)(~(unsigned)(best & 0xFFFFFFFFull));
        g_best[l] = n; g_pat[l] = mapping[n];
    }
}

// ---- gather-fold: paired-s full-lane iteration ------------------------------
// Round-12: the old s-loop had <=32 of 64 lanes active per iteration (d =
// x+PAD-s in [0,32) gates a 32-wide window) — ~43% lane activity over 74
// iterations per wave. Two s-values 37 apart have DISJOINT active windows
// ([s-10,s+21] vs [s+27,s+58]), so each iteration now processes the pair
// (s, s+37): t = x+PAD-s; t in [0,32) -> row s, col t; t in [37,69) -> row
// s+37, col t-37; else idle. 74 -> 37 iterations, ~92% lane activity, loads
// stay coalesced (two 128B row-segments per instruction). Per-lane coverage
// is exactly the same s-set as before (verified at x=0/63/64/90/127); only
// fp add order changes (~ulp noise, << 2e-3 tolerance).
__global__ __launch_bounds__(128)
void gather_fold(const float* __restrict__ mem2)
{
    const int y = blockIdx.x;
    const int c = blockIdx.y;
    const int q = blockIdx.z;
    const int x = threadIdx.x;            // 0..127
    const int wv = x >> 6;

    const int py_lo = max(0, y - 21);
    const int py_hi = min(LWID - 1, y + PAD_);
    const int p0 = py_lo + q * 8;
    const int p1 = min(p0 + 8, py_hi + 1);
    const int nrows = (p1 > p0) ? (p1 - p0) : 0;

    __shared__ int patS[8 * LWID];
    for (int i = x; i < nrows * LWID; i += 128) {
        int rr = i / LWID, cc = i - rr * LWID;
        patS[i] = g_pat[(p0 + rr) * LWID + cc];
    }
    __syncthreads();

    const int slo = wv ? 43 : 0;          // wave s-range: [slo, slo+73], paired

    float acc = 0.f;
    for (int py = p0; py < p1; ++py) {
        const int kh = y + PAD_ - py;                 // 0..31
        const int dbase = c * 1024 + kh * 32;
        const int* prow = &patS[(py - p0) * LWID];
        for (int i = 0; i < 37; ++i) {
            int s = slo + i;
            int t = x + PAD_ - s;
            int hi = (t >= 37) ? 37 : 0;
            int d = t - hi;
            if ((unsigned)d < 32u)
                acc += mem2[(size_t)prow[s + hi] * D_ + dbase + d];
        }
    }
    g_part[q][((size_t)y * W_ + x) * C_ + c] = acc;
}

// ---- sum partials + global max ----------------------------------------------
__global__ __launch_bounds__(256)
void maxfind(float* __restrict__ out)
{
    int i = blockIdx.x * 256 + threadIdx.x;           // 192*256 == 49152 exact
    float v = g_part[0][i] + g_part[1][i] + g_part[2][i] + g_part[3][i];
    out[i] = v;
    float m = v;
    #pragma unroll
    for (int s = 32; s >= 1; s >>= 1) m = fmaxf(m, __shfl_xor(m, s, 64));
    if ((threadIdx.x & 63) == 0) atomicMax(&g_max, sortable(m));
}

__global__ __launch_bounds__(256)
void normalize_k(float* __restrict__ out)
{
    int i = blockIdx.x * 256 + threadIdx.x;
    float mx = unsortable(g_max);
    out[i] = out[i] / mx;
}

extern "C" void kernel_launch(void* const* d_in, const int* in_sizes, int n_in,
                              void* d_out, int out_size, void* d_ws, size_t ws_size,
                              hipStream_t stream)
{
    const float* img     = (const float*)d_in[0];   // (128,128,3)
    const float* mem     = (const float*)d_in[1];   // (4096,3072)
    const float* mem2    = (const float*)d_in[2];   // (4096,3072)
    const int*   mapping = (const int*)d_in[3];     // (4096,)
    float* out = (float*)d_out;                     // (128,128,3)

    prep<<<NMEM_ + 16 * 3 * QROWS, 256, 0, stream>>>(img, mem);
    gemm_scores<<<(NMEM_ / 128) * (LPAD / 128), 256, 0, stream>>>();
    reduce_rescue<<<L_, 256, 0, stream>>>(img, mem, mapping);
    gather_fold<<<dim3(H_, C_, 4), 128, 0, stream>>>(mem2);
    maxfind<<<192, 256, 0, stream>>>(out);
    normalize_k<<<192, 256, 0, stream>>>(out);
}